// Round 5
// baseline (136.610 us; speedup 1.0000x reference)
//
#include <hip/hip_runtime.h>

#define NN 50000
#define NPAD 50048   // 782*64, pad so GEMM row tiles stay in-bounds
#define NE 320000
#define D 256
#define CAP 64       // per-node in-edge capacity; deg ~ Poisson(6.4)

typedef __bf16 bf16x8 __attribute__((ext_vector_type(8)));
typedef float f32x4 __attribute__((ext_vector_type(4)));

__device__ __forceinline__ unsigned short f2bf(float f) {
    unsigned u = __builtin_bit_cast(unsigned, f);
    unsigned r = u + 0x7FFFu + ((u >> 16) & 1u);   // RNE
    return (unsigned short)(r >> 16);
}
__device__ __forceinline__ float bf2f(unsigned short h) {
    return __builtin_bit_cast(float, (unsigned)h << 16);
}
__device__ __forceinline__ float bflo(unsigned u) {
    return __builtin_bit_cast(float, u << 16);
}
__device__ __forceinline__ float bfhi(unsigned u) {
    return __builtin_bit_cast(float, u & 0xFFFF0000u);
}
__device__ __forceinline__ unsigned packbf(float lo, float hi) {
    return (unsigned)f2bf(lo) | ((unsigned)f2bf(hi) << 16);
}

// WTT[j][k] (bf16, row stride 512): k<256 -> w1[j][k]; k>=256 -> (w2@w3)[j][k-256]
// bvec[j] = (w2 @ b3)[j]  (f32)
__global__ __launch_bounds__(256) void prep_weights(
        const float* __restrict__ w1, const float* __restrict__ w2,
        const float* __restrict__ w3, const float* __restrict__ b3,
        unsigned short* __restrict__ WTT, float* __restrict__ bvec) {
    const int j = blockIdx.x;    // output row of WTT
    const int k = threadIdx.x;
    __shared__ float w2row[D];
    __shared__ float red[D];
    w2row[k] = w2[j * D + k];
    __syncthreads();
    float acc = 0.f;
    #pragma unroll 8
    for (int o = 0; o < D; ++o) acc += w2row[o] * w3[o * D + k];   // coalesced in k
    WTT[(size_t)j * 512 + k]       = f2bf(w1[j * D + k]);
    WTT[(size_t)j * 512 + D + k]   = f2bf(acc);
    red[k] = w2row[k] * b3[k];
    __syncthreads();
    for (int s = 128; s > 0; s >>= 1) {
        if (k < s) red[k] += red[k + s];
        __syncthreads();
    }
    if (k == 0) bvec[j] = red[0];
}

// also zeroes cnt (runs before fill_csr on the stream)
__global__ __launch_bounds__(256) void convert_x(
        const float* __restrict__ x, unsigned short* __restrict__ xbf,
        int* __restrict__ cnt) {
    const size_t gid = (size_t)blockIdx.x * 256 + threadIdx.x;
    if (gid < NN) cnt[gid] = 0;
    const size_t i = gid * 8;
    if (i >= (size_t)NN * D) return;
    const float4 a = *reinterpret_cast<const float4*>(x + i);
    const float4 b = *reinterpret_cast<const float4*>(x + i + 4);
    ushort4 o0 = {f2bf(a.x), f2bf(a.y), f2bf(a.z), f2bf(a.w)};
    ushort4 o1 = {f2bf(b.x), f2bf(b.y), f2bf(b.z), f2bf(b.w)};
    *reinterpret_cast<ushort4*>(xbf + i)     = o0;
    *reinterpret_cast<ushort4*>(xbf + i + 4) = o1;
}

__global__ __launch_bounds__(256) void fill_csr(
        const int* __restrict__ ei, int* __restrict__ csr, int* __restrict__ cnt) {
    const int e = blockIdx.x * 256 + threadIdx.x;
    if (e >= NE) return;
    const int src = ei[e];
    const int dst = ei[NE + e];
    const int pos = atomicAdd(cnt + dst, 1);
    if (pos < CAP) csr[(size_t)dst * CAP + pos] = src;
}

// Fused gather + GEMM:
//   out[64 x 256 tile] = [x | agg] (64 x 512) @ WTT^T + deg*bvec
// Phase 1: 4 waves cooperatively gather-sum agg rows into swizzled LDS (bf16).
// Phase 2: register GEMM; x-half A and all B loaded DIRECT global->VGPR
//          (B is L2-resident; x lines fully consumed per kt), agg from LDS.
// Only one barrier per block; no per-kt drains -> blocks at different phases
// overlap gather latency with MFMA on the same CU.
__global__ __launch_bounds__(256) void gemm_fused(
        const unsigned short* __restrict__ xbf, const unsigned short* __restrict__ WTT,
        const float* __restrict__ bvec, const int* __restrict__ cnt,
        const int* __restrict__ csr, float* __restrict__ out) {
    // [64 rows][32 units of 16B]; unit swizzle: u' = u ^ (row&7)
    __shared__ __align__(16) unsigned short aggL[64 * 256];   // 32 KB

    const int tid  = threadIdx.x;
    const int w    = tid >> 6;     // wave id = wn (output col block)
    const int lane = tid & 63;
    const int gr0  = blockIdx.x * 64;

    // ---------- phase 1: gather agg rows ----------
    {
        const int sub = lane >> 4;     // 0..3: row within quad
        const int l16 = lane & 15;
        #pragma unroll
        for (int pass = 0; pass < 4; ++pass) {
            const int r  = w * 16 + pass * 4 + sub;   // 0..63
            const int gr = gr0 + r;
            int d = 0;
            if (gr < NN) { d = cnt[gr]; if (d > CAP) d = CAP; }
            const int* __restrict__ row = csr + (size_t)gr * CAP;
            float a[16];
            #pragma unroll
            for (int j = 0; j < 16; ++j) a[j] = 0.f;
            int i = 0;
            for (; i + 2 <= d; i += 2) {
                const int s0 = row[i], s1 = row[i + 1];
                const uint4 p0 = *reinterpret_cast<const uint4*>(xbf + (size_t)s0 * D + l16 * 8);
                const uint4 p1 = *reinterpret_cast<const uint4*>(xbf + (size_t)s0 * D + 128 + l16 * 8);
                const uint4 q0 = *reinterpret_cast<const uint4*>(xbf + (size_t)s1 * D + l16 * 8);
                const uint4 q1 = *reinterpret_cast<const uint4*>(xbf + (size_t)s1 * D + 128 + l16 * 8);
                a[0] += bflo(p0.x) + bflo(q0.x); a[1] += bfhi(p0.x) + bfhi(q0.x);
                a[2] += bflo(p0.y) + bflo(q0.y); a[3] += bfhi(p0.y) + bfhi(q0.y);
                a[4] += bflo(p0.z) + bflo(q0.z); a[5] += bfhi(p0.z) + bfhi(q0.z);
                a[6] += bflo(p0.w) + bflo(q0.w); a[7] += bfhi(p0.w) + bfhi(q0.w);
                a[8]  += bflo(p1.x) + bflo(q1.x); a[9]  += bfhi(p1.x) + bfhi(q1.x);
                a[10] += bflo(p1.y) + bflo(q1.y); a[11] += bfhi(p1.y) + bfhi(q1.y);
                a[12] += bflo(p1.z) + bflo(q1.z); a[13] += bfhi(p1.z) + bfhi(q1.z);
                a[14] += bflo(p1.w) + bflo(q1.w); a[15] += bfhi(p1.w) + bfhi(q1.w);
            }
            if (i < d) {
                const int s0 = row[i];
                const uint4 p0 = *reinterpret_cast<const uint4*>(xbf + (size_t)s0 * D + l16 * 8);
                const uint4 p1 = *reinterpret_cast<const uint4*>(xbf + (size_t)s0 * D + 128 + l16 * 8);
                a[0] += bflo(p0.x); a[1] += bfhi(p0.x);
                a[2] += bflo(p0.y); a[3] += bfhi(p0.y);
                a[4] += bflo(p0.z); a[5] += bfhi(p0.z);
                a[6] += bflo(p0.w); a[7] += bfhi(p0.w);
                a[8]  += bflo(p1.x); a[9]  += bfhi(p1.x);
                a[10] += bflo(p1.y); a[11] += bfhi(p1.y);
                a[12] += bflo(p1.z); a[13] += bfhi(p1.z);
                a[14] += bflo(p1.w); a[15] += bfhi(p1.w);
            }
            uint4 o0 = {packbf(a[0], a[1]),  packbf(a[2], a[3]),
                        packbf(a[4], a[5]),  packbf(a[6], a[7])};
            uint4 o1 = {packbf(a[8], a[9]),  packbf(a[10], a[11]),
                        packbf(a[12], a[13]), packbf(a[14], a[15])};
            const int u0 = l16 ^ (r & 7);          // units 0..15  (cols 0..127)
            const int u1 = (16 + l16) ^ (r & 7);   // units 16..31 (cols 128..255)
            *reinterpret_cast<uint4*>(&aggL[(r * 32 + u0) * 8]) = o0;
            *reinterpret_cast<uint4*>(&aggL[(r * 32 + u1) * 8]) = o1;
        }
    }
    __syncthreads();

    // ---------- phase 2: register GEMM ----------
    f32x4 acc[4][4];
    #pragma unroll
    for (int a = 0; a < 4; ++a)
        #pragma unroll
        for (int b = 0; b < 4; ++b) acc[a][b] = (f32x4)0.f;

    const int l16g = lane & 15;
    const int g4   = lane >> 4;    // 0..3

    // x-half: K 0..255, A direct from global
    #pragma unroll
    for (int kt = 0; kt < 4; ++kt) {
        #pragma unroll
        for (int kh = 0; kh < 2; ++kh) {
            const int ko = kt * 64 + kh * 32 + g4 * 8;   // k elem offset
            bf16x8 af[4], bfr[4];
            #pragma unroll
            for (int f = 0; f < 4; ++f) {
                const int ra = gr0 + f * 16 + l16g;
                af[f] = *reinterpret_cast<const bf16x8*>(xbf + ((size_t)ra << 8) + ko);
                const int rb = w * 64 + f * 16 + l16g;
                bfr[f] = *reinterpret_cast<const bf16x8*>(WTT + ((size_t)rb << 9) + ko);
            }
            #pragma unroll
            for (int fm = 0; fm < 4; ++fm)
                #pragma unroll
                for (int fn = 0; fn < 4; ++fn)
                    acc[fm][fn] = __builtin_amdgcn_mfma_f32_16x16x32_bf16(
                        af[fm], bfr[fn], acc[fm][fn], 0, 0, 0);
        }
    }
    // agg-half: K 256..511, A from swizzled LDS
    #pragma unroll
    for (int kt = 0; kt < 4; ++kt) {
        #pragma unroll
        for (int kh = 0; kh < 2; ++kh) {
            const int cb = kt * 8 + kh * 4 + g4;         // unit 0..31
            bf16x8 af[4], bfr[4];
            #pragma unroll
            for (int f = 0; f < 4; ++f) {
                const int r = f * 16 + l16g;
                af[f] = *reinterpret_cast<const bf16x8*>(
                    &aggL[(r * 32 + (cb ^ (r & 7))) * 8]);
                const int rb = w * 64 + f * 16 + l16g;
                bfr[f] = *reinterpret_cast<const bf16x8*>(
                    WTT + ((size_t)rb << 9) + 256 + cb * 8);
            }
            #pragma unroll
            for (int fm = 0; fm < 4; ++fm)
                #pragma unroll
                for (int fn = 0; fn < 4; ++fn)
                    acc[fm][fn] = __builtin_amdgcn_mfma_f32_16x16x32_bf16(
                        af[fm], bfr[fn], acc[fm][fn], 0, 0, 0);
        }
    }

    // ---------- epilogue: out = acc + deg*bvec ----------
    const int col0 = w * 64 + l16g;
    float bv[4];
    #pragma unroll
    for (int fn = 0; fn < 4; ++fn) bv[fn] = bvec[col0 + fn * 16];
    #pragma unroll
    for (int fm = 0; fm < 4; ++fm) {
        #pragma unroll
        for (int i = 0; i < 4; ++i) {
            const int row = gr0 + fm * 16 + g4 * 4 + i;
            if (row < NN) {
                const float dg = (float)cnt[row];
                float* op = out + ((size_t)row << 8) + col0;
                #pragma unroll
                for (int fn = 0; fn < 4; ++fn)
                    op[fn * 16] = acc[fm][fn][i] + dg * bv[fn];
            }
        }
    }
}

extern "C" void kernel_launch(void* const* d_in, const int* in_sizes, int n_in,
                              void* d_out, int out_size, void* d_ws, size_t ws_size,
                              hipStream_t stream) {
    const float* x  = (const float*)d_in[0];
    const int*   ei = (const int*)d_in[1];
    const float* w1 = (const float*)d_in[2];
    const float* w2 = (const float*)d_in[3];
    const float* w3 = (const float*)d_in[4];
    const float* b3 = (const float*)d_in[5];
    float* out = (float*)d_out;

    unsigned short* xbf = (unsigned short*)d_ws;                 // NPAD*256
    unsigned short* WTT = xbf + (size_t)NPAD * D;                // 256*512
    float* bvec = (float*)(WTT + (size_t)D * 512);               // 256
    int*   cnt  = (int*)(bvec + D);                              // NN
    int*   csr  = cnt + NN;                                      // NN*CAP

    prep_weights<<<D, 256, 0, stream>>>(w1, w2, w3, b3, WTT, bvec);
    convert_x<<<(NN * D) / (256 * 8), 256, 0, stream>>>(x, xbf, cnt);
    fill_csr<<<(NE + 255) / 256, 256, 0, stream>>>(ei, csr, cnt);
    gemm_fused<<<NPAD / 64, 256, 0, stream>>>(xbf, WTT, bvec, cnt, csr, out);
}